// Round 8
// baseline (136.547 us; speedup 1.0000x reference)
//
#include <hip/hip_runtime.h>

// ---------------- types / helpers ----------------
typedef unsigned short u16;
typedef float f32x4 __attribute__((ext_vector_type(4)));
typedef short bf16x8 __attribute__((ext_vector_type(8)));

__device__ __forceinline__ u16 f2bf(float f) {
    unsigned u = __float_as_uint(f);
    u = (u + 0x7FFFu + ((u >> 16) & 1u)) >> 16;
    return (u16)u;
}

#define LOG2E 1.4426950408889634f

#if __has_builtin(__builtin_amdgcn_exp2f)
__device__ __forceinline__ float exp2_fast(float x) { return __builtin_amdgcn_exp2f(x); }
#else
__device__ __forceinline__ float exp2_fast(float x) { return __expf(x * 0.6931471805599453f); }
#endif

__device__ __forceinline__ unsigned pack2bf(float a, float b) {
    unsigned ua = __float_as_uint(a) + 0x8000u;
    unsigned ub = __float_as_uint(b) + 0x8000u;
#if __has_builtin(__builtin_amdgcn_perm)
    return __builtin_amdgcn_perm(ub, ua, 0x07060302u);
#else
    return ((ua >> 16) & 0xFFFFu) | (ub & 0xFFFF0000u);
#endif
}

#if __has_builtin(__builtin_amdgcn_cvt_pk_bf16_f32)
typedef __bf16 bf2_t __attribute__((ext_vector_type(2)));
__device__ __forceinline__ unsigned cvtpk(float a, float b) {
    bf2_t r = __builtin_amdgcn_cvt_pk_bf16_f32(a, b);
    return __builtin_bit_cast(unsigned, r);
}
#else
__device__ __forceinline__ unsigned cvtpk(float a, float b) { return pack2bf(a, b); }
#endif

__device__ __forceinline__ bf16x8 bc8(uint4 u) { return __builtin_bit_cast(bf16x8, u); }

// async 16B/lane global->LDS DMA; lds dst = wave-uniform base + lane*16.
#if __has_builtin(__builtin_amdgcn_global_load_lds)
typedef const __attribute__((address_space(1))) void* as1cv;
typedef __attribute__((address_space(3))) void* as3v;
__device__ __forceinline__ void dma16(const void* g, void* lds_base, int lane) {
    __builtin_amdgcn_global_load_lds((as1cv)g, (as3v)lds_base, 16, 0, 0);
}
#else
__device__ __forceinline__ void dma16(const void* g, void* lds_base, int lane) {
    *(uint4*)((char*)lds_base + lane * 16) = *(const uint4*)g;
}
#endif

// Problem constants. DEDUP: only 3136 unique keys; multiplicity {1,2,4} folded
// into V (pre-scaled) + counts row. All intermediate layouts are 16-row fragment
// tiles so every global access is contiguous per wave.
#define BB 2
#define HH 56
#define SQ 3136
#define CROWN 3584

// workspace offsets (u16 units)
#define WS_Q    0         // 392 tiles * 4096
#define WS_K    1605632   // 2 b * 200 tiles * 4096 (196 real + 4 pad)
#define WS_V    3244032   // 16 bh * 200 rg * 512
#define WS_WT   4882432   // 3*65536 fragment-packed weights
#define WS_CB   5079040   // 3584 u16 bf16 counts
#define WS_XB   5082624   // 392 tiles * 4096 bf16 x

// ---------------- kernel 0: fused prep (weights + x + crow + pad zeros) ------------
// blocks 0..47: weight fragment-pack job (mode=bid/16, kx=((bid%16)>>2)*64, dx=(bid&3)*64)
// blocks 48..439: x -> bf16 fragment tile (tile = bid-48)
__global__ __launch_bounds__(256) void prep_kernel(const float* __restrict__ x,
                                                   const float* __restrict__ Wq,
                                                   const float* __restrict__ Wk,
                                                   const float* __restrict__ Wv,
                                                   u16* __restrict__ wtf,
                                                   u16* __restrict__ kbf,
                                                   u16* __restrict__ vbf,
                                                   u16* __restrict__ crow,
                                                   u16* __restrict__ xbf) {
    __shared__ __align__(16) char SM[17408];
    int tid = threadIdx.x;
    int bid = blockIdx.x;

    if (bid < 48) {
        // ---- weight fragment-pack ----
        u16 (*T)[68] = (u16(*)[68])SM;
        int mode = bid >> 4, rem = bid & 15;
        int kx = (rem >> 2) * 64, dx = (rem & 3) * 64;
        const float* W = (mode == 0) ? Wq : ((mode == 1) ? Wk : Wv);
        float sc = (mode == 0) ? LOG2E : 1.0f;
        int r16 = tid >> 4, c4 = (tid & 15) * 4;
#pragma unroll
        for (int p = 0; p < 4; ++p) {
            int kr = p * 16 + r16;
            float4 f = *(const float4*)&W[(size_t)(kx + kr) * 256 + dx + c4];
            T[kr][c4 + 0] = f2bf(f.x * sc);
            T[kr][c4 + 1] = f2bf(f.y * sc);
            T[kr][c4 + 2] = f2bf(f.z * sc);
            T[kr][c4 + 3] = f2bf(f.w * sc);
        }
        __syncthreads();
        int l16 = tid & 15, nt_loc = (tid >> 4) & 3, quad = (tid >> 6) & 3;
#pragma unroll
        for (int s_loc = 0; s_loc < 2; ++s_loc) {
            int k0 = s_loc * 32 + quad * 8;
            int d_loc = nt_loc * 16 + l16;
            u16 tmp[8];
#pragma unroll
            for (int j = 0; j < 8; ++j) tmp[j] = T[k0 + j][d_loc];
            int d = dx + d_loc;
            int nz = d >> 7, ntg = (d >> 4) & 7;
            int s = (kx >> 5) + s_loc;
            int f = (nz * 8 + s) * 8 + ntg;
            int L = quad * 16 + l16;
            *(uint4*)&wtf[(size_t)mode * 65536 + (size_t)f * 512 + (size_t)L * 8] = *(uint4*)tmp;
        }
        uint4 z4 = (uint4){0, 0, 0, 0};
        if (mode == 0 && kx == 0 && dx == 0) {
            for (int i = tid; i < 4096; i += 256) {
                int bb = i >> 11, rem2 = i & 2047;
                int t = 196 + (rem2 >> 9), off = (rem2 & 511) * 8;
                *(uint4*)&kbf[(((size_t)(bb * 200 + t)) << 12) + off] = z4;
            }
        }
        if (mode == 1 && kx == 0 && dx == 0) {
            for (int i = tid; i < CROWN; i += 256) {
                u16 v = 0;
                if (i < SQ) {
                    int rr = i / 56, cc = i - rr * 56;
                    int mr = (((rr >= 1) && (rr <= 3)) || ((rr >= 52) && (rr <= 54))) ? 2 : 1;
                    int mc = (((cc >= 1) && (cc <= 3)) || ((cc >= 52) && (cc <= 54))) ? 2 : 1;
                    int prod = mr * mc;
                    v = (prod == 1) ? (u16)0x3F80 : ((prod == 2) ? (u16)0x4000 : (u16)0x4080);
                }
                crow[i] = v;
            }
        }
        if (mode == 2 && kx == 0 && dx == 0) {
            for (int i = tid; i < 4096; i += 256) {
                int bh = i >> 8, rem2 = i & 255;
                int rgp = 196 + (rem2 >> 6), off = (rem2 & 63) * 8;
                *(uint4*)&vbf[(((size_t)(bh * 200 + rgp)) << 9) + off] = z4;
            }
        }
    } else {
        // ---- x -> bf16 fragment tile ----
        float (*T)[256] = (float(*)[256])SM;
        int tile = bid - 48;
        int r = tid >> 4, c0 = (tid & 15) * 16;
        const float* src = x + ((size_t)tile * 16 + r) * 256 + c0;
#pragma unroll
        for (int k = 0; k < 4; ++k)
            *(float4*)&T[r][c0 + k * 4] = *(const float4*)&src[k * 4];
        __syncthreads();
#pragma unroll
        for (int e = 0; e < 2; ++e) {
            int g = tid + e * 256;                  // granule 0..511
            int s = g >> 6, L = g & 63;
            const float* row = &T[L & 15][s * 32 + (L >> 4) * 8];
            uint4 pk = (uint4){pack2bf(row[0], row[1]), pack2bf(row[2], row[3]),
                               pack2bf(row[4], row[5]), pack2bf(row[6], row[7])};
            *(uint4*)&xbf[(size_t)tile * 4096 + (size_t)g * 8] = pk;
        }
    }
}

// ---------------- kernel 1: projections (UNCHANGED from round 7) -------------------
__global__ __launch_bounds__(256, 4) void proj_kernel(const u16* __restrict__ xbf,
                                                      const u16* __restrict__ wtf,
                                                      const float* __restrict__ bq,
                                                      const float* __restrict__ bk,
                                                      const float* __restrict__ bv,
                                                      u16* __restrict__ qbf,
                                                      u16* __restrict__ kbf,
                                                      u16* __restrict__ vbf) {
    int mode = blockIdx.y, nz = blockIdx.z;
    int mbase = blockIdx.x * 64;
    int tid = threadIdx.x;
    int wave = tid >> 6, lane = tid & 63, quad = (tid >> 4) & 3, l16 = tid & 15;
    const float* bias = (mode == 0) ? bq : ((mode == 1) ? bk : bv);
    float wsc = (mode == 0) ? LOG2E : 1.0f;
    const u16* wf = wtf + (size_t)mode * 65536 + (size_t)nz * 32768 + (size_t)lane * 8;
    const u16* xt = xbf + (((size_t)(mbase >> 4) + wave) << 12);   // tile base (*4096)

    f32x4 acc[8];
#pragma unroll
    for (int i = 0; i < 8; i++) acc[i] = (f32x4){0.f, 0.f, 0.f, 0.f};

#pragma unroll
    for (int s = 0; s < 8; ++s) {
        bf16x8 af = *(const bf16x8*)&xt[(s << 9) + lane * 8];
        if (mode == 2) {
#pragma unroll
            for (int nt = 0; nt < 8; nt++) {
                bf16x8 bfrag = *(const bf16x8*)&wf[(s * 8 + nt) * 512];
                acc[nt] = __builtin_amdgcn_mfma_f32_16x16x32_bf16(af, bfrag, acc[nt], 0, 0, 0);
            }
        } else {
#pragma unroll
            for (int nt = 0; nt < 8; nt++) {
                bf16x8 bfrag = *(const bf16x8*)&wf[(s * 8 + nt) * 512];
                acc[nt] = __builtin_amdgcn_mfma_f32_16x16x32_bf16(bfrag, af, acc[nt], 0, 0, 0);
            }
        }
    }

    if (mode == 2) {
        int b_ = (mbase >= SQ) ? 1 : 0;
        int kp0 = mbase - b_ * SQ + wave * 16 + quad * 4;
        int rg = (mbase - b_ * SQ + wave * 16) >> 4;
        float mult[4];
#pragma unroll
        for (int p = 0; p < 4; ++p) {
            int kp = kp0 + p;
            int rr = kp / 56, cc = kp - rr * 56;
            float mr = (((rr >= 1) && (rr <= 3)) || ((rr >= 52) && (rr <= 54))) ? 2.f : 1.f;
            float mc = (((cc >= 1) && (cc <= 3)) || ((cc >= 52) && (cc <= 54))) ? 2.f : 1.f;
            mult[p] = mr * mc;
        }
#pragma unroll
        for (int nt = 0; nt < 8; nt++) {
            int c = nz * 128 + nt * 16 + l16;
            float bvv = bias[c];
            int h_idx = nz * 4 + (nt >> 1);
            int L = (nt & 1) * 16 + l16 + ((quad >> 1) & 1) * 32;
            float va0 = (acc[nt][0] + bvv) * mult[0];
            float va1 = (acc[nt][1] + bvv) * mult[1];
            float va2 = (acc[nt][2] + bvv) * mult[2];
            float va3 = (acc[nt][3] + bvv) * mult[3];
            uint2 pk = (uint2){pack2bf(va0, va1), pack2bf(va2, va3)};
            *(uint2*)&vbf[(((size_t)((b_ * 8 + h_idx) * 200 + rg)) << 9) + L * 8 + (quad & 1) * 4] = pk;
        }
    } else {
        u16* outp = (mode == 0) ? qbf : kbf;
        int t = (mbase >> 4) + wave;
        int tt = (mode == 0) ? t : (t + (t >= 196 ? 4 : 0));
#pragma unroll
        for (int nt = 0; nt < 8; nt++) {
            int c0 = nz * 128 + nt * 16 + quad * 4;
            float4 b4 = *(const float4*)&bias[c0];
            float v0 = acc[nt][0] + b4.x * wsc;
            float v1 = acc[nt][1] + b4.y * wsc;
            float v2 = acc[nt][2] + b4.z * wsc;
            float v3 = acc[nt][3] + b4.w * wsc;
            int s_idx = nz * 4 + (nt >> 1);
            int Lrow = ((nt & 1) * 2 + (quad >> 1)) * 16 + l16;
            uint2 pk = (uint2){pack2bf(v0, v1), pack2bf(v2, v3)};
            *(uint2*)&outp[(((size_t)(tt * 8 + s_idx)) << 9) + Lrow * 8 + (quad & 1) * 4] = pk;
        }
    }
}

// ---------------- kernel 2: flash attention (round-7 structure, bh-split) ----------
// DIAGNOSTIC SPLIT: launched twice with bh_base 0/8, grid (8,49) each. Each half
// ~26-28us so any slower dispatch (proj?) surfaces in rocprof top-5.
__global__ __launch_bounds__(512, 6) void attn_kernel(const u16* __restrict__ qb,
                                                      const u16* __restrict__ kb,
                                                      const u16* __restrict__ vtb,
                                                      const u16* __restrict__ crow,
                                                      const float* __restrict__ x,
                                                      const float* __restrict__ gammap,
                                                      float* __restrict__ out,
                                                      int bh_base) {
    __shared__ __align__(16) u16 S[19968];   // 2 bufs x 8192 (K 4096 + V 4096), cnt @16384

    int tid = threadIdx.x;
    int w = tid >> 6, lane = tid & 63, quad = lane >> 4, l16 = lane & 15;
    int g = w & 3, qh = w >> 2;
    int bh = bh_base + blockIdx.x;
    int b = bh >> 3, h = bh & 7;

    int qtile = b * 196 + blockIdx.y * 4 + qh * 2;
    bf16x8 qf[2];
#pragma unroll
    for (int i = 0; i < 2; ++i)
        qf[i] = *(const bf16x8*)&qb[(((size_t)(qtile + i) * 8 + h) << 9) + lane * 8];

    const u16* kg = kb + ((size_t)(b * 200) << 12);             // b's K tile base
    const u16* vg = vtb + (((size_t)((b * 8 + h) * 200)) << 9); // (b,h) V tile base

    f32x4 o[2][2], lv[2];
#pragma unroll
    for (int i = 0; i < 2; ++i) {
        o[i][0] = (f32x4){0.f, 0.f, 0.f, 0.f};
        o[i][1] = (f32x4){0.f, 0.f, 0.f, 0.f};
        lv[i]   = (f32x4){0.f, 0.f, 0.f, 0.f};
    }

    // wave w stages K tile w and V tile w of chunk r_ch: both 1KB LINEAR
    auto stage = [&](int r_ch, int buf) {
        u16* base = &S[buf * 8192];
        int rg = r_ch * 8 + w;
        dma16(kg + (((size_t)rg * 8 + h) << 9) + lane * 8, base + w * 512, lane);
        dma16(vg + (((size_t)rg) << 9) + lane * 8, base + 4096 + w * 512, lane);
    };

    int tA = g, tB = g + 4;
    int vOffA = tA * 512 + (((quad >> 1) * 32 + l16) << 3) + (quad & 1) * 4;
    int vOffB = tB * 512 + (((quad >> 1) * 32 + l16) << 3) + (quad & 1) * 4;

    auto round_body = [&](int r, int bR) {
        const u16* Kl = &S[bR * 8192];
        const u16* Vl = Kl + 4096;
        const u16* cnt = &S[16384] + r * 128;
        f32x4 z = (f32x4){0.f, 0.f, 0.f, 0.f};

        float pA[2][4];
        {
            bf16x8 kfA = *(const bf16x8*)&Kl[tA * 512 + lane * 8];
            f32x4 eA0 = __builtin_amdgcn_mfma_f32_16x16x32_bf16(kfA, qf[0], z, 0, 0, 0);
            f32x4 eA1 = __builtin_amdgcn_mfma_f32_16x16x32_bf16(kfA, qf[1], z, 0, 0, 0);
#pragma unroll
            for (int j = 0; j < 4; ++j) pA[0][j] = exp2_fast(eA0[j]);
#pragma unroll
            for (int j = 0; j < 4; ++j) pA[1][j] = exp2_fast(eA1[j]);
        }
        float pB[2][4];
        {
            bf16x8 kfB = *(const bf16x8*)&Kl[tB * 512 + lane * 8];
            f32x4 eB0 = __builtin_amdgcn_mfma_f32_16x16x32_bf16(kfB, qf[0], z, 0, 0, 0);
            f32x4 eB1 = __builtin_amdgcn_mfma_f32_16x16x32_bf16(kfB, qf[1], z, 0, 0, 0);
#pragma unroll
            for (int j = 0; j < 4; ++j) pB[0][j] = exp2_fast(eB0[j]);
#pragma unroll
            for (int j = 0; j < 4; ++j) pB[1][j] = exp2_fast(eB1[j]);
        }
        uint2 ca = *(const uint2*)&cnt[tA * 16 + quad * 4];
        uint2 cc = *(const uint2*)&cnt[tB * 16 + quad * 4];
        bf16x8 cf = bc8((uint4){ca.x, ca.y, cc.x, cc.y});
        uint2 wA0 = *(const uint2*)&Vl[vOffA];
        uint2 wB0 = *(const uint2*)&Vl[vOffB];
        bf16x8 V0 = bc8((uint4){wA0.x, wA0.y, wB0.x, wB0.y});
        uint2 wA1 = *(const uint2*)&Vl[vOffA + 128];
        uint2 wB1 = *(const uint2*)&Vl[vOffB + 128];
        bf16x8 V1 = bc8((uint4){wA1.x, wA1.y, wB1.x, wB1.y});

#pragma unroll
        for (int i = 0; i < 2; ++i) {
            bf16x8 pa = bc8((uint4){cvtpk(pA[i][0], pA[i][1]), cvtpk(pA[i][2], pA[i][3]),
                                    cvtpk(pB[i][0], pB[i][1]), cvtpk(pB[i][2], pB[i][3])});
            o[i][0] = __builtin_amdgcn_mfma_f32_16x16x32_bf16(pa, V0, o[i][0], 0, 0, 0);
            o[i][1] = __builtin_amdgcn_mfma_f32_16x16x32_bf16(pa, V1, o[i][1], 0, 0, 0);
            lv[i]   = __builtin_amdgcn_mfma_f32_16x16x32_bf16(pa, cf, lv[i], 0, 0, 0);
        }
    };

    // prologue: counts (7 x 1KB across waves 0-6, linear) + round 0
    if (w < 7) dma16(crow + w * 512 + lane * 8, (char*)&S[16384] + w * 1024, lane);
    stage(0, 0);

    for (int r = 0; r < 25; ++r) {
        asm volatile("s_waitcnt vmcnt(0)" ::: "memory");   // own stage(r) landed
        __builtin_amdgcn_s_barrier();                      // raw: prefetches stay in flight
        asm volatile("" ::: "memory");
        if (r + 1 < 25) stage(r + 1, (r + 1) & 1);         // flies during body(r)
        round_body(r, r & 1);
    }
    __syncthreads();                           // all waves done; LDS reusable

    // ---- merge 4 roles per q-half (two independent trees) ----
    float* mg = (float*)&S[0];
    {
        int slot = ((qh * 2 + (g & 1)) * 64 + lane) * 24;
        if (g >= 2) {
            *(f32x4*)&mg[slot + 0]  = o[0][0];
            *(f32x4*)&mg[slot + 4]  = o[0][1];
            *(f32x4*)&mg[slot + 8]  = o[1][0];
            *(f32x4*)&mg[slot + 12] = o[1][1];
            *(f32x4*)&mg[slot + 16] = lv[0];
            *(f32x4*)&mg[slot + 20] = lv[1];
        }
        __syncthreads();
        if (g < 2) {
            o[0][0] += *(const f32x4*)&mg[slot + 0];
            o[0][1] += *(const f32x4*)&mg[slot + 4];
            o[1][0] += *(const f32x4*)&mg[slot + 8];
            o[1][1] += *(const f32x4*)&mg[slot + 12];
            lv[0]   += *(const f32x4*)&mg[slot + 16];
            lv[1]   += *(const f32x4*)&mg[slot + 20];
        }
        __syncthreads();
    }
    {
        int slot = (qh * 64 + lane) * 24;
        if (g == 1) {
            *(f32x4*)&mg[slot + 0]  = o[0][0];
            *(f32x4*)&mg[slot + 4]  = o[0][1];
            *(f32x4*)&mg[slot + 8]  = o[1][0];
            *(f32x4*)&mg[slot + 12] = o[1][1];
            *(f32x4*)&mg[slot + 16] = lv[0];
            *(f32x4*)&mg[slot + 20] = lv[1];
        }
        __syncthreads();
        if (g == 0) {
            o[0][0] += *(const f32x4*)&mg[slot + 0];
            o[0][1] += *(const f32x4*)&mg[slot + 4];
            o[1][0] += *(const f32x4*)&mg[slot + 8];
            o[1][1] += *(const f32x4*)&mg[slot + 12];
            lv[0]   += *(const f32x4*)&mg[slot + 16];
            lv[1]   += *(const f32x4*)&mg[slot + 20];
            float gam = gammap[0];
#pragma unroll
            for (int i = 0; i < 2; ++i) {
#pragma unroll
                for (int r2 = 0; r2 < 4; ++r2) {
                    float scl = gam / lv[i][r2];
                    int q = blockIdx.y * 64 + qh * 32 + i * 16 + quad * 4 + r2;
                    size_t base = ((size_t)(b * SQ + q) << 8) + h * 32 + l16;
                    out[base]      = o[i][0][r2] * scl + x[base];
                    out[base + 16] = o[i][1][r2] * scl + x[base + 16];
                }
            }
        }
    }
}

// ---------------- launcher ----------------
extern "C" void kernel_launch(void* const* d_in, const int* in_sizes, int n_in,
                              void* d_out, int out_size, void* d_ws, size_t ws_size,
                              hipStream_t stream) {
    const float* x     = (const float*)d_in[0];
    const float* Wq    = (const float*)d_in[1];
    const float* bq    = (const float*)d_in[2];
    const float* Wk    = (const float*)d_in[3];
    const float* bk    = (const float*)d_in[4];
    const float* Wv    = (const float*)d_in[5];
    const float* bv    = (const float*)d_in[6];
    const float* gamma = (const float*)d_in[7];
    float* out = (float*)d_out;

    u16* ws   = (u16*)d_ws;
    u16* qbf  = ws + WS_Q;
    u16* kbf  = ws + WS_K;
    u16* vbf  = ws + WS_V;
    u16* wtf  = ws + WS_WT;
    u16* crow = ws + WS_CB;
    u16* xbf  = ws + WS_XB;

    prep_kernel<<<440, 256, 0, stream>>>(x, Wq, Wk, Wv, wtf, kbf, vbf, crow, xbf);
    proj_kernel<<<dim3(98, 3, 2), 256, 0, stream>>>(xbf, wtf, bq, bk, bv, qbf, kbf, vbf);
    attn_kernel<<<dim3(8, 49), 512, 0, stream>>>(qbf, kbf, vbf, crow, x, gamma, out, 0);
    attn_kernel<<<dim3(8, 49), 512, 0, stream>>>(qbf, kbf, vbf, crow, x, gamma, out, 8);
}

// Round 9
// 128.257 us; speedup vs baseline: 1.0646x; 1.0646x over previous
//
#include <hip/hip_runtime.h>

// ---------------- types / helpers ----------------
typedef unsigned short u16;
typedef float f32x4 __attribute__((ext_vector_type(4)));
typedef short bf16x8 __attribute__((ext_vector_type(8)));

__device__ __forceinline__ u16 f2bf(float f) {
    unsigned u = __float_as_uint(f);
    u = (u + 0x7FFFu + ((u >> 16) & 1u)) >> 16;
    return (u16)u;
}

#define LOG2E 1.4426950408889634f

#if __has_builtin(__builtin_amdgcn_exp2f)
__device__ __forceinline__ float exp2_fast(float x) { return __builtin_amdgcn_exp2f(x); }
#else
__device__ __forceinline__ float exp2_fast(float x) { return __expf(x * 0.6931471805599453f); }
#endif

__device__ __forceinline__ unsigned pack2bf(float a, float b) {
    unsigned ua = __float_as_uint(a) + 0x8000u;
    unsigned ub = __float_as_uint(b) + 0x8000u;
#if __has_builtin(__builtin_amdgcn_perm)
    return __builtin_amdgcn_perm(ub, ua, 0x07060302u);
#else
    return ((ua >> 16) & 0xFFFFu) | (ub & 0xFFFF0000u);
#endif
}

#if __has_builtin(__builtin_amdgcn_cvt_pk_bf16_f32)
typedef __bf16 bf2_t __attribute__((ext_vector_type(2)));
__device__ __forceinline__ unsigned cvtpk(float a, float b) {
    bf2_t r = __builtin_amdgcn_cvt_pk_bf16_f32(a, b);
    return __builtin_bit_cast(unsigned, r);
}
#else
__device__ __forceinline__ unsigned cvtpk(float a, float b) { return pack2bf(a, b); }
#endif

__device__ __forceinline__ bf16x8 bc8(uint4 u) { return __builtin_bit_cast(bf16x8, u); }

// async 16B/lane global->LDS DMA; lds dst = wave-uniform base + lane*16.
#if __has_builtin(__builtin_amdgcn_global_load_lds)
typedef const __attribute__((address_space(1))) void* as1cv;
typedef __attribute__((address_space(3))) void* as3v;
__device__ __forceinline__ void dma16(const void* g, void* lds_base, int lane) {
    __builtin_amdgcn_global_load_lds((as1cv)g, (as3v)lds_base, 16, 0, 0);
}
#else
__device__ __forceinline__ void dma16(const void* g, void* lds_base, int lane) {
    *(uint4*)((char*)lds_base + lane * 16) = *(const uint4*)g;
}
#endif

// Problem constants. DEDUP: only 3136 unique keys; multiplicity {1,2,4} folded
// into V (pre-scaled) + counts row. All intermediate layouts are 16-row fragment
// tiles so every global access is contiguous per wave.
#define BB 2
#define HH 56
#define SQ 3136
#define CROWN 3584

// workspace offsets (u16 units)
#define WS_Q    0         // 392 tiles * 4096
#define WS_K    1605632   // 2 b * 200 tiles * 4096 (196 real + 4 pad)
#define WS_V    3244032   // 16 bh * 200 rg * 512
#define WS_WT   4882432   // 3*65536 fragment-packed weights
#define WS_CB   5079040   // 3584 u16 bf16 counts
#define WS_XB   5082624   // 392 tiles * 4096 bf16 x

// ---------------- kernel 0: fused prep (weights + x + crow + pad zeros) ------------
__global__ __launch_bounds__(256) void prep_kernel(const float* __restrict__ x,
                                                   const float* __restrict__ Wq,
                                                   const float* __restrict__ Wk,
                                                   const float* __restrict__ Wv,
                                                   u16* __restrict__ wtf,
                                                   u16* __restrict__ kbf,
                                                   u16* __restrict__ vbf,
                                                   u16* __restrict__ crow,
                                                   u16* __restrict__ xbf) {
    __shared__ __align__(16) char SM[17408];
    int tid = threadIdx.x;
    int bid = blockIdx.x;

    if (bid < 48) {
        u16 (*T)[68] = (u16(*)[68])SM;
        int mode = bid >> 4, rem = bid & 15;
        int kx = (rem >> 2) * 64, dx = (rem & 3) * 64;
        const float* W = (mode == 0) ? Wq : ((mode == 1) ? Wk : Wv);
        float sc = (mode == 0) ? LOG2E : 1.0f;
        int r16 = tid >> 4, c4 = (tid & 15) * 4;
#pragma unroll
        for (int p = 0; p < 4; ++p) {
            int kr = p * 16 + r16;
            float4 f = *(const float4*)&W[(size_t)(kx + kr) * 256 + dx + c4];
            T[kr][c4 + 0] = f2bf(f.x * sc);
            T[kr][c4 + 1] = f2bf(f.y * sc);
            T[kr][c4 + 2] = f2bf(f.z * sc);
            T[kr][c4 + 3] = f2bf(f.w * sc);
        }
        __syncthreads();
        int l16 = tid & 15, nt_loc = (tid >> 4) & 3, quad = (tid >> 6) & 3;
#pragma unroll
        for (int s_loc = 0; s_loc < 2; ++s_loc) {
            int k0 = s_loc * 32 + quad * 8;
            int d_loc = nt_loc * 16 + l16;
            u16 tmp[8];
#pragma unroll
            for (int j = 0; j < 8; ++j) tmp[j] = T[k0 + j][d_loc];
            int d = dx + d_loc;
            int nz = d >> 7, ntg = (d >> 4) & 7;
            int s = (kx >> 5) + s_loc;
            int f = (nz * 8 + s) * 8 + ntg;
            int L = quad * 16 + l16;
            *(uint4*)&wtf[(size_t)mode * 65536 + (size_t)f * 512 + (size_t)L * 8] = *(uint4*)tmp;
        }
        uint4 z4 = (uint4){0, 0, 0, 0};
        if (mode == 0 && kx == 0 && dx == 0) {
            for (int i = tid; i < 4096; i += 256) {
                int bb = i >> 11, rem2 = i & 2047;
                int t = 196 + (rem2 >> 9), off = (rem2 & 511) * 8;
                *(uint4*)&kbf[(((size_t)(bb * 200 + t)) << 12) + off] = z4;
            }
        }
        if (mode == 1 && kx == 0 && dx == 0) {
            for (int i = tid; i < CROWN; i += 256) {
                u16 v = 0;
                if (i < SQ) {
                    int rr = i / 56, cc = i - rr * 56;
                    int mr = (((rr >= 1) && (rr <= 3)) || ((rr >= 52) && (rr <= 54))) ? 2 : 1;
                    int mc = (((cc >= 1) && (cc <= 3)) || ((cc >= 52) && (cc <= 54))) ? 2 : 1;
                    int prod = mr * mc;
                    v = (prod == 1) ? (u16)0x3F80 : ((prod == 2) ? (u16)0x4000 : (u16)0x4080);
                }
                crow[i] = v;
            }
        }
        if (mode == 2 && kx == 0 && dx == 0) {
            for (int i = tid; i < 4096; i += 256) {
                int bh = i >> 8, rem2 = i & 255;
                int rgp = 196 + (rem2 >> 6), off = (rem2 & 63) * 8;
                *(uint4*)&vbf[(((size_t)(bh * 200 + rgp)) << 9) + off] = z4;
            }
        }
    } else {
        float (*T)[256] = (float(*)[256])SM;
        int tile = bid - 48;
        int r = tid >> 4, c0 = (tid & 15) * 16;
        const float* src = x + ((size_t)tile * 16 + r) * 256 + c0;
#pragma unroll
        for (int k = 0; k < 4; ++k)
            *(float4*)&T[r][c0 + k * 4] = *(const float4*)&src[k * 4];
        __syncthreads();
#pragma unroll
        for (int e = 0; e < 2; ++e) {
            int g = tid + e * 256;                  // granule 0..511
            int s = g >> 6, L = g & 63;
            const float* row = &T[L & 15][s * 32 + (L >> 4) * 8];
            uint4 pk = (uint4){pack2bf(row[0], row[1]), pack2bf(row[2], row[3]),
                               pack2bf(row[4], row[5]), pack2bf(row[6], row[7])};
            *(uint4*)&xbf[(size_t)tile * 4096 + (size_t)g * 8] = pk;
        }
    }
}

// ---------------- kernel 1: projections (UNCHANGED from round 7) -------------------
__global__ __launch_bounds__(256, 4) void proj_kernel(const u16* __restrict__ xbf,
                                                      const u16* __restrict__ wtf,
                                                      const float* __restrict__ bq,
                                                      const float* __restrict__ bk,
                                                      const float* __restrict__ bv,
                                                      u16* __restrict__ qbf,
                                                      u16* __restrict__ kbf,
                                                      u16* __restrict__ vbf) {
    int mode = blockIdx.y, nz = blockIdx.z;
    int mbase = blockIdx.x * 64;
    int tid = threadIdx.x;
    int wave = tid >> 6, lane = tid & 63, quad = (tid >> 4) & 3, l16 = tid & 15;
    const float* bias = (mode == 0) ? bq : ((mode == 1) ? bk : bv);
    float wsc = (mode == 0) ? LOG2E : 1.0f;
    const u16* wf = wtf + (size_t)mode * 65536 + (size_t)nz * 32768 + (size_t)lane * 8;
    const u16* xt = xbf + (((size_t)(mbase >> 4) + wave) << 12);   // tile base (*4096)

    f32x4 acc[8];
#pragma unroll
    for (int i = 0; i < 8; i++) acc[i] = (f32x4){0.f, 0.f, 0.f, 0.f};

#pragma unroll
    for (int s = 0; s < 8; ++s) {
        bf16x8 af = *(const bf16x8*)&xt[(s << 9) + lane * 8];
        if (mode == 2) {
#pragma unroll
            for (int nt = 0; nt < 8; nt++) {
                bf16x8 bfrag = *(const bf16x8*)&wf[(s * 8 + nt) * 512];
                acc[nt] = __builtin_amdgcn_mfma_f32_16x16x32_bf16(af, bfrag, acc[nt], 0, 0, 0);
            }
        } else {
#pragma unroll
            for (int nt = 0; nt < 8; nt++) {
                bf16x8 bfrag = *(const bf16x8*)&wf[(s * 8 + nt) * 512];
                acc[nt] = __builtin_amdgcn_mfma_f32_16x16x32_bf16(bfrag, af, acc[nt], 0, 0, 0);
            }
        }
    }

    if (mode == 2) {
        int b_ = (mbase >= SQ) ? 1 : 0;
        int kp0 = mbase - b_ * SQ + wave * 16 + quad * 4;
        int rg = (mbase - b_ * SQ + wave * 16) >> 4;
        float mult[4];
#pragma unroll
        for (int p = 0; p < 4; ++p) {
            int kp = kp0 + p;
            int rr = kp / 56, cc = kp - rr * 56;
            float mr = (((rr >= 1) && (rr <= 3)) || ((rr >= 52) && (rr <= 54))) ? 2.f : 1.f;
            float mc = (((cc >= 1) && (cc <= 3)) || ((cc >= 52) && (cc <= 54))) ? 2.f : 1.f;
            mult[p] = mr * mc;
        }
#pragma unroll
        for (int nt = 0; nt < 8; nt++) {
            int c = nz * 128 + nt * 16 + l16;
            float bvv = bias[c];
            int h_idx = nz * 4 + (nt >> 1);
            int L = (nt & 1) * 16 + l16 + ((quad >> 1) & 1) * 32;
            float va0 = (acc[nt][0] + bvv) * mult[0];
            float va1 = (acc[nt][1] + bvv) * mult[1];
            float va2 = (acc[nt][2] + bvv) * mult[2];
            float va3 = (acc[nt][3] + bvv) * mult[3];
            uint2 pk = (uint2){pack2bf(va0, va1), pack2bf(va2, va3)};
            *(uint2*)&vbf[(((size_t)((b_ * 8 + h_idx) * 200 + rg)) << 9) + L * 8 + (quad & 1) * 4] = pk;
        }
    } else {
        u16* outp = (mode == 0) ? qbf : kbf;
        int t = (mbase >> 4) + wave;
        int tt = (mode == 0) ? t : (t + (t >= 196 ? 4 : 0));
#pragma unroll
        for (int nt = 0; nt < 8; nt++) {
            int c0 = nz * 128 + nt * 16 + quad * 4;
            float4 b4 = *(const float4*)&bias[c0];
            float v0 = acc[nt][0] + b4.x * wsc;
            float v1 = acc[nt][1] + b4.y * wsc;
            float v2 = acc[nt][2] + b4.z * wsc;
            float v3 = acc[nt][3] + b4.w * wsc;
            int s_idx = nz * 4 + (nt >> 1);
            int Lrow = ((nt & 1) * 2 + (quad >> 1)) * 16 + l16;
            uint2 pk = (uint2){pack2bf(v0, v1), pack2bf(v2, v3)};
            *(uint2*)&outp[(((size_t)(tt * 8 + s_idx)) << 9) + Lrow * 8 + (quad & 1) * 4] = pk;
        }
    }
}

// ---------------- kernel 2: flash attention (4 de-phased waves, ZERO loop barriers) -
// grid (16 bh, 49 qsub), 256 thr = 4 waves. Wave w owns ALL 64 queries and key
// tiles {w, w+4} of each 128-key round — and stages EXACTLY those tiles itself,
// so all loop-time LDS regions are wave-private: no barriers, waves free-run and
// their exp/LDS/MFMA phases interleave across the SIMD (kills phase convoys).
// Depth-1 prefetch per wave: stage(r+1) issued, then vmcnt(4) completes stage(r)
// while stage(r+1) flies under body(r). 2 bufs suffice (regions private).
// T5 setprio around MFMA clusters. launch_bounds(256,4): 128-reg cap, ~112 used.
__global__ __launch_bounds__(256, 4) void attn_kernel(const u16* __restrict__ qb,
                                                      const u16* __restrict__ kb,
                                                      const u16* __restrict__ vtb,
                                                      const u16* __restrict__ crow,
                                                      const float* __restrict__ x,
                                                      const float* __restrict__ gammap,
                                                      float* __restrict__ out) {
    __shared__ __align__(16) u16 S[19968];   // 2 bufs x 8192 (K 4096 + V 4096), cnt @16384

    int tid = threadIdx.x;
    int w = tid >> 6, lane = tid & 63, quad = lane >> 4, l16 = lane & 15;
    int bh = blockIdx.x;
    int b = bh >> 3, h = bh & 7;
    int qsub = blockIdx.y * 64;

    int qtile = b * 196 + blockIdx.y * 4;
    bf16x8 qf[4];
#pragma unroll
    for (int i = 0; i < 4; ++i)
        qf[i] = *(const bf16x8*)&qb[(((size_t)(qtile + i) * 8 + h) << 9) + lane * 8];

    const u16* kg = kb + ((size_t)(b * 200) << 12);             // b's K tile base
    const u16* vg = vtb + (((size_t)((b * 8 + h) * 200)) << 9); // (b,h) V tile base

    f32x4 o[4][2], lv[4];
#pragma unroll
    for (int i = 0; i < 4; ++i) {
        o[i][0] = (f32x4){0.f, 0.f, 0.f, 0.f};
        o[i][1] = (f32x4){0.f, 0.f, 0.f, 0.f};
        lv[i]   = (f32x4){0.f, 0.f, 0.f, 0.f};
    }

    int tA = w, tB = w + 4;
    // wave w stages K tiles {w, w+4} and V tiles {w, w+4}: 4 x 1KB linear DMAs
    auto stage = [&](int r_ch, int buf) {
        u16* base = &S[buf * 8192];
        int rgA = r_ch * 8 + tA, rgB = r_ch * 8 + tB;
        dma16(kg + (((size_t)rgA * 8 + h) << 9) + lane * 8, base + tA * 512, lane);
        dma16(kg + (((size_t)rgB * 8 + h) << 9) + lane * 8, base + tB * 512, lane);
        dma16(vg + (((size_t)rgA) << 9) + lane * 8, base + 4096 + tA * 512, lane);
        dma16(vg + (((size_t)rgB) << 9) + lane * 8, base + 4096 + tB * 512, lane);
    };

    int vOffA = tA * 512 + (((quad >> 1) * 32 + l16) << 3) + (quad & 1) * 4;
    int vOffB = tB * 512 + (((quad >> 1) * 32 + l16) << 3) + (quad & 1) * 4;

    auto round_body = [&](int r, int bR) {
        const u16* Kl = &S[bR * 8192];
        const u16* Vl = Kl + 4096;
        const u16* cnt = &S[16384] + r * 128;
        f32x4 z = (f32x4){0.f, 0.f, 0.f, 0.f};
        unsigned paw[4][4];

        {
            bf16x8 kfA = *(const bf16x8*)&Kl[tA * 512 + lane * 8];
            f32x4 eA[4];
            __builtin_amdgcn_s_setprio(1);
#pragma unroll
            for (int i = 0; i < 4; ++i)
                eA[i] = __builtin_amdgcn_mfma_f32_16x16x32_bf16(kfA, qf[i], z, 0, 0, 0);
            __builtin_amdgcn_s_setprio(0);
#pragma unroll
            for (int i = 0; i < 4; ++i) {
                paw[i][0] = cvtpk(exp2_fast(eA[i][0]), exp2_fast(eA[i][1]));
                paw[i][1] = cvtpk(exp2_fast(eA[i][2]), exp2_fast(eA[i][3]));
            }
        }
        {
            bf16x8 kfB = *(const bf16x8*)&Kl[tB * 512 + lane * 8];
            f32x4 eB[4];
            __builtin_amdgcn_s_setprio(1);
#pragma unroll
            for (int i = 0; i < 4; ++i)
                eB[i] = __builtin_amdgcn_mfma_f32_16x16x32_bf16(kfB, qf[i], z, 0, 0, 0);
            __builtin_amdgcn_s_setprio(0);
#pragma unroll
            for (int i = 0; i < 4; ++i) {
                paw[i][2] = cvtpk(exp2_fast(eB[i][0]), exp2_fast(eB[i][1]));
                paw[i][3] = cvtpk(exp2_fast(eB[i][2]), exp2_fast(eB[i][3]));
            }
        }
        uint2 ca = *(const uint2*)&cnt[tA * 16 + quad * 4];
        uint2 cc = *(const uint2*)&cnt[tB * 16 + quad * 4];
        bf16x8 cf = bc8((uint4){ca.x, ca.y, cc.x, cc.y});
        uint2 wA0 = *(const uint2*)&Vl[vOffA];
        uint2 wB0 = *(const uint2*)&Vl[vOffB];
        bf16x8 V0 = bc8((uint4){wA0.x, wA0.y, wB0.x, wB0.y});
        uint2 wA1 = *(const uint2*)&Vl[vOffA + 128];
        uint2 wB1 = *(const uint2*)&Vl[vOffB + 128];
        bf16x8 V1 = bc8((uint4){wA1.x, wA1.y, wB1.x, wB1.y});

        __builtin_amdgcn_s_setprio(1);
#pragma unroll
        for (int i = 0; i < 4; ++i) {
            bf16x8 pa = bc8((uint4){paw[i][0], paw[i][1], paw[i][2], paw[i][3]});
            o[i][0] = __builtin_amdgcn_mfma_f32_16x16x32_bf16(pa, V0, o[i][0], 0, 0, 0);
            o[i][1] = __builtin_amdgcn_mfma_f32_16x16x32_bf16(pa, V1, o[i][1], 0, 0, 0);
            lv[i]   = __builtin_amdgcn_mfma_f32_16x16x32_bf16(pa, cf, lv[i], 0, 0, 0);
        }
        __builtin_amdgcn_s_setprio(0);
    };

    // prologue: counts (wave w stages chunks w and w+4<7) + stage(0); ONE barrier
    {
        dma16(crow + w * 512 + lane * 8, (char*)&S[16384] + w * 1024, lane);
        if (w + 4 < 7)
            dma16(crow + (w + 4) * 512 + lane * 8, (char*)&S[16384] + (w + 4) * 1024, lane);
    }
    stage(0, 0);
    __syncthreads();                 // drains all DMA (cnt + buf0) for all waves

    for (int r = 0; r < 25; ++r) {
        if (r + 1 < 25) {
            stage(r + 1, (r + 1) & 1);                         // 4 DMAs, flies under body(r)
            asm volatile("s_waitcnt vmcnt(4)" ::: "memory");   // stage(r) complete
        } else {
            asm volatile("s_waitcnt vmcnt(0)" ::: "memory");
        }
        round_body(r, r & 1);
    }
    __syncthreads();                 // all waves done; LDS reusable

    // ---- two-stage merge of 4 key-roles via LDS ----
    float* mg = (float*)&S[0];
    {
        int slot = ((w & 1) * 64 + lane) * 48;
        if (w >= 2) {
#pragma unroll
            for (int i = 0; i < 4; ++i) {
                *(f32x4*)&mg[slot + i * 8]      = o[i][0];
                *(f32x4*)&mg[slot + i * 8 + 4]  = o[i][1];
                *(f32x4*)&mg[slot + 32 + i * 4] = lv[i];
            }
        }
        __syncthreads();
        if (w < 2) {
#pragma unroll
            for (int i = 0; i < 4; ++i) {
                o[i][0] += *(const f32x4*)&mg[slot + i * 8];
                o[i][1] += *(const f32x4*)&mg[slot + i * 8 + 4];
                lv[i]   += *(const f32x4*)&mg[slot + 32 + i * 4];
            }
        }
        __syncthreads();
    }
    {
        int slot = lane * 48;
        if (w == 1) {
#pragma unroll
            for (int i = 0; i < 4; ++i) {
                *(f32x4*)&mg[slot + i * 8]      = o[i][0];
                *(f32x4*)&mg[slot + i * 8 + 4]  = o[i][1];
                *(f32x4*)&mg[slot + 32 + i * 4] = lv[i];
            }
        }
        __syncthreads();
        if (w == 0) {
            float gam = gammap[0];
#pragma unroll
            for (int i = 0; i < 4; ++i) {
                o[i][0] += *(const f32x4*)&mg[slot + i * 8];
                o[i][1] += *(const f32x4*)&mg[slot + i * 8 + 4];
                lv[i]   += *(const f32x4*)&mg[slot + 32 + i * 4];
#pragma unroll
                for (int r2 = 0; r2 < 4; ++r2) {
                    float scl = gam / lv[i][r2];
                    int q = qsub + i * 16 + quad * 4 + r2;
                    size_t base = ((size_t)(b * SQ + q) << 8) + h * 32 + l16;
                    out[base]      = o[i][0][r2] * scl + x[base];
                    out[base + 16] = o[i][1][r2] * scl + x[base + 16];
                }
            }
        }
    }
}

// ---------------- launcher ----------------
extern "C" void kernel_launch(void* const* d_in, const int* in_sizes, int n_in,
                              void* d_out, int out_size, void* d_ws, size_t ws_size,
                              hipStream_t stream) {
    const float* x     = (const float*)d_in[0];
    const float* Wq    = (const float*)d_in[1];
    const float* bq    = (const float*)d_in[2];
    const float* Wk    = (const float*)d_in[3];
    const float* bk    = (const float*)d_in[4];
    const float* Wv    = (const float*)d_in[5];
    const float* bv    = (const float*)d_in[6];
    const float* gamma = (const float*)d_in[7];
    float* out = (float*)d_out;

    u16* ws   = (u16*)d_ws;
    u16* qbf  = ws + WS_Q;
    u16* kbf  = ws + WS_K;
    u16* vbf  = ws + WS_V;
    u16* wtf  = ws + WS_WT;
    u16* crow = ws + WS_CB;
    u16* xbf  = ws + WS_XB;

    prep_kernel<<<440, 256, 0, stream>>>(x, Wq, Wk, Wv, wtf, kbf, vbf, crow, xbf);
    proj_kernel<<<dim3(98, 3, 2), 256, 0, stream>>>(xbf, wtf, bq, bk, bv, qbf, kbf, vbf);
    attn_kernel<<<dim3(16, 49), 256, 0, stream>>>(qbf, kbf, vbf, crow, x, gamma, out);
}